// Round 6
// baseline (121.721 us; speedup 1.0000x reference)
//
#include <hip/hip_runtime.h>
#include <math.h>

#define KS    65536
#define TS    96
#define TPB   256
#define NBLK  (KS / TPB)      /* 256 */

#define MSR 0.196f            /* 9.8 * 0.02 (f64 -> f32) */
#define WSM 17.0f
#define DTF 0.02f

/* Branchless sincos: Cody-Waite pi/2 reduction + Taylor deg-7/8. err ~1e-7 */
static __device__ __forceinline__ void fast_sincosf(float x, float& s, float& c) {
  float nf = __builtin_rintf(x * 0.63661977f);
  int   q  = (int)nf;
  float r  = __builtin_fmaf(nf, -1.5703125f, x);
  r = __builtin_fmaf(nf, -4.837512969970703125e-4f, r);
  r = __builtin_fmaf(nf, -7.54978995489188216e-8f, r);
  float r2 = r * r;
  float sw = __builtin_fmaf(r2, -1.98412698e-4f, 8.33333310e-3f);
  sw = __builtin_fmaf(r2, sw, -1.66666672e-1f);
  sw = __builtin_fmaf(r2, sw, 1.0f);
  float sinr = r * sw;
  float cw = __builtin_fmaf(r2, 2.48015873e-5f, -1.38888889e-3f);
  cw = __builtin_fmaf(r2, cw, 4.16666679e-2f);
  cw = __builtin_fmaf(r2, cw, -0.5f);
  float cosr = __builtin_fmaf(r2, cw, 1.0f);
  const bool swq = (q & 1) != 0;
  float sb = swq ? cosr : sinr;
  float cb = swq ? sinr : cosr;
  unsigned ssign = ((unsigned)q << 30) & 0x80000000u;
  unsigned csign = ((unsigned)(q + 1) << 30) & 0x80000000u;
  s = __uint_as_float(__float_as_uint(sb) ^ ssign);
  c = __uint_as_float(__float_as_uint(cb) ^ csign);
}

static __device__ __forceinline__ float clipc(float v, float b) {
  return fminf(fmaxf(v, -b), b);
}

/* ws layout (floats):
   [0, KS*4)            per-k {cost_total, noise[k,0,0], noise[k,0,1], pad}
   [KS*4, KS*4+NBLK)    per-block cost min
   [KS*4+NBLK, +3)      accumulators {sum_w, sum_w*n0, sum_w*n1}            */

__global__ __launch_bounds__(TPB, 1) void mppi_rollout(
    const float* __restrict__ state, const float* __restrict__ U,
    const float* __restrict__ noise, const float* __restrict__ nsi,
    const float* __restrict__ bev,   const float* __restrict__ goal,
    float* __restrict__ ws)
{
  const float MCRf = (float)(tan(30.0 / 57.3) / (0.24 + 0.24) * 20.0 * 0.02);

  __shared__ float  s_bev[2500];
  __shared__ float4 s_ug[97];        /* {u0*MCR, u1*WSM, g0, g1}; [96]=pad */

  const int tid = threadIdx.x;
  if (tid < 97) {
    float u0 = 0.f, u1 = 0.f;
    if (tid < 95) { u0 = U[(tid + 1) * 2 + 0]; u1 = U[(tid + 1) * 2 + 1]; }
    float4 g;
    g.x = u0 * MCRf; g.y = u1 * WSM;
    g.z = u0 * nsi[0] + u1 * nsi[1];
    g.w = u0 * nsi[2] + u1 * nsi[3];
    s_ug[tid] = g;
  }
  for (int i = tid; i < 2500; i += TPB) s_bev[i] = bev[i];
  if (blockIdx.x == 0 && tid < 3) ws[(size_t)KS * 4 + NBLK + tid] = 0.f;
  __syncthreads();

  const int k = blockIdx.x * TPB + tid;
  const float4* __restrict__ nrow = (const float4*)(noise + (size_t)k * (TS * 2));

  const float gx = goal[0], gy = goal[1];
  float x = state[0], yy = state[1], yaw = state[5];

  /* noise pair-ring, depth 4 (A,B used this iter; C,D in flight) */
  float4 A0 = nrow[0], A1 = nrow[1];
  float4 B0 = nrow[2], B1 = nrow[3];
  float4 C0 = nrow[4], C1 = nrow[5];
  float4 D0 = nrow[6], D1 = nrow[7];
  const float n00 = A0.x, n01 = A0.y;

  float4 u1 = s_ug[1], u2 = s_ug[2], u3 = s_ug[3], u4 = s_ug[4];

  float craw, sraw, gz, gw;
  {
    float4 u0 = s_ug[0];
    craw = __builtin_fmaf(A0.x, MCRf, u0.x);
    sraw = __builtin_fmaf(A0.y, WSM,  u0.y);
    gz = u0.z; gw = u0.w;
  }
  float c_acc = 0.f, s_acc = 0.f;
  float a0 = 0.f, a1 = 0.f, a2 = 0.f, a3 = 0.f;
  float dist_sum = 0.f, map_sum = 0.f, dlast = 0.f;
  float pp0 = 0.f, pp1 = 0.f, pp2 = 0.f, pp3 = 0.f;

  for (int i = 0; i < 23; ++i) {
    /* prefetch next-iter ug and noise early (consumed 1 / 3 iters later) */
    const int tb = 4 * i + 5;
    float4 f1 = s_ug[tb], f2 = s_ug[tb + 1], f3 = s_ug[tb + 2], f4 = s_ug[tb + 3];
    int pf = 2 * i + 8; if (pf > 46) pf = 46;
    const float4 nD0 = nrow[pf], nD1 = nrow[pf + 1];

    /* phase 1: raw curvature/speed at t+1..t+4 (independent) */
    float rc1 = __builtin_fmaf(A0.z, MCRf, u1.x), rs1 = __builtin_fmaf(A0.w, WSM, u1.y);
    float rc2 = __builtin_fmaf(A1.x, MCRf, u2.x), rs2 = __builtin_fmaf(A1.y, WSM, u2.y);
    float rc3 = __builtin_fmaf(A1.z, MCRf, u3.x), rs3 = __builtin_fmaf(A1.w, WSM, u3.y);
    float rc4 = __builtin_fmaf(B0.x, MCRf, u4.x), rs4 = __builtin_fmaf(B0.y, WSM, u4.y);

    /* phase 2: clipped diffs + tree partial sums -> c,s at each step */
    float dc0 = clipc(rc1 - craw, MCRf), dc1 = clipc(rc2 - rc1, MCRf);
    float dc2 = clipc(rc3 - rc2, MCRf),  dc3 = clipc(rc4 - rc3, MCRf);
    float ds0 = clipc(rs1 - sraw, MSR),  ds1 = clipc(rs2 - rs1, MSR);
    float ds2 = clipc(rs3 - rs2, MSR),   ds3 = clipc(rs4 - rs3, MSR);
    craw = rc4; sraw = rs4;
    float ec12 = dc0 + dc1, ec123 = ec12 + dc2, ec1234 = ec12 + (dc2 + dc3);
    float es12 = ds0 + ds1, es123 = es12 + ds2, es1234 = es12 + (ds2 + ds3);
    float c1 = c_acc + dc0, c2 = c_acc + ec12, c3 = c_acc + ec123, c4 = c_acc + ec1234;
    float s1 = s_acc + ds0, s2 = s_acc + es12, s3 = s_acc + es123, s4 = s_acc + es1234;
    c_acc = c4; s_acc = s4;

    /* phase 3: yaw via tree partial sums */
    float q1 = s1 * c1, q2 = s2 * c2, q3 = s3 * c3, q4 = s4 * c4;
    float q12 = q1 + q2, q123 = q12 + q3, q1234 = q12 + (q3 + q4);
    float w1 = __builtin_fmaf(q1,    DTF, yaw);
    float w2 = __builtin_fmaf(q12,   DTF, yaw);
    float w3 = __builtin_fmaf(q123,  DTF, yaw);
    float w4 = __builtin_fmaf(q1234, DTF, yaw);
    yaw = w4;

    /* phase 4: four independent sincos chains */
    float sn1, cs1, sn2, cs2, sn3, cs3, sn4, cs4;
    fast_sincosf(w1, sn1, cs1);
    fast_sincosf(w2, sn2, cs2);
    fast_sincosf(w3, sn3, cs3);
    fast_sincosf(w4, sn4, cs4);

    /* phase 5: x,y via tree partial sums */
    float sd1 = s1 * DTF, sd2 = s2 * DTF, sd3 = s3 * DTF, sd4 = s4 * DTF;
    float xi1 = sd1 * cs1, xi2 = sd2 * cs2, xi3 = sd3 * cs3, xi4 = sd4 * cs4;
    float yi1 = sd1 * sn1, yi2 = sd2 * sn2, yi3 = sd3 * sn3, yi4 = sd4 * sn4;
    float xs12 = xi1 + xi2, xs123 = xs12 + xi3, xs1234 = xs12 + (xi3 + xi4);
    float ys12 = yi1 + yi2, ys123 = ys12 + yi3, ys1234 = ys12 + (yi3 + yi4);
    float x1 = x + xi1, x2 = x + xs12, x3 = x + xs123, x4 = x + xs1234;
    float y1 = yy + yi1, y2 = yy + ys12, y3 = yy + ys123, y4 = yy + ys1234;
    x = x4; yy = y4;

    /* phase 6: distances (4 independent sqrt) */
    float dx1 = x1 - gx, dy1 = y1 - gy, dx2 = x2 - gx, dy2 = y2 - gy;
    float dx3 = x3 - gx, dy3 = y3 - gy, dx4 = x4 - gx, dy4 = y4 - gy;
    float d1 = __builtin_sqrtf(__builtin_fmaf(dy1, dy1, dx1 * dx1));
    float d2 = __builtin_sqrtf(__builtin_fmaf(dy2, dy2, dx2 * dx2));
    float d3 = __builtin_sqrtf(__builtin_fmaf(dy3, dy3, dx3 * dx3));
    float d4 = __builtin_sqrtf(__builtin_fmaf(dy4, dy4, dx4 * dx4));
    dist_sum += (d1 + d2) + (d3 + d4);

    /* phase 7: BEV indices; consume last iter's gathers, issue this iter's */
    float fx1 = fminf(fmaxf(__builtin_fmaf(x1, 2.5f, 25.f), 0.f), 49.f);
    float fy1 = fminf(fmaxf(__builtin_fmaf(y1, 2.5f, 25.f), 0.f), 49.f);
    float fx2 = fminf(fmaxf(__builtin_fmaf(x2, 2.5f, 25.f), 0.f), 49.f);
    float fy2 = fminf(fmaxf(__builtin_fmaf(y2, 2.5f, 25.f), 0.f), 49.f);
    float fx3 = fminf(fmaxf(__builtin_fmaf(x3, 2.5f, 25.f), 0.f), 49.f);
    float fy3 = fminf(fmaxf(__builtin_fmaf(y3, 2.5f, 25.f), 0.f), 49.f);
    float fx4 = fminf(fmaxf(__builtin_fmaf(x4, 2.5f, 25.f), 0.f), 49.f);
    float fy4 = fminf(fmaxf(__builtin_fmaf(y4, 2.5f, 25.f), 0.f), 49.f);
    map_sum += (pp0 + pp1) + (pp2 + pp3);
    pp0 = s_bev[(int)fy1 * 50 + (int)fx1];
    pp1 = s_bev[(int)fy2 * 50 + (int)fx2];
    pp2 = s_bev[(int)fy3 * 50 + (int)fx3];
    pp3 = s_bev[(int)fy4 * 50 + (int)fx4];

    /* phase 8: action cost (4 split accumulators) */
    a0 = __builtin_fmaf(A0.x, gz,   a0); a1 = __builtin_fmaf(A0.y, gw,   a1);
    a2 = __builtin_fmaf(A0.z, u1.z, a2); a3 = __builtin_fmaf(A0.w, u1.w, a3);
    a0 = __builtin_fmaf(A1.x, u2.z, a0); a1 = __builtin_fmaf(A1.y, u2.w, a1);
    a2 = __builtin_fmaf(A1.z, u3.z, a2); a3 = __builtin_fmaf(A1.w, u3.w, a3);
    gz = u4.z; gw = u4.w;

    /* shift rings */
    u1 = f1; u2 = f2; u3 = f3; u4 = f4;
    A0 = B0; A1 = B1; B0 = C0; B1 = C1; C0 = D0; C1 = D1; D0 = nD0; D1 = nD1;
  }

  /* peeled last iteration: t = 92,93,94,95; u1..u4 = ug[93..96] */
  {
    float rc1 = __builtin_fmaf(A0.z, MCRf, u1.x), rs1 = __builtin_fmaf(A0.w, WSM, u1.y);
    float rc2 = __builtin_fmaf(A1.x, MCRf, u2.x), rs2 = __builtin_fmaf(A1.y, WSM, u2.y);
    float rc3 = __builtin_fmaf(A1.z, MCRf, u3.x), rs3 = __builtin_fmaf(A1.w, WSM, u3.y);

    float dc0 = clipc(rc1 - craw, MCRf), dc1 = clipc(rc2 - rc1, MCRf);
    float dc2 = clipc(rc3 - rc2, MCRf);
    float ds0 = clipc(rs1 - sraw, MSR),  ds1 = clipc(rs2 - rs1, MSR);
    float ds2 = clipc(rs3 - rs2, MSR);
    float ec12 = dc0 + dc1, ec123 = ec12 + dc2;
    float es12 = ds0 + ds1, es123 = es12 + ds2;
    float c1 = c_acc + dc0, c2 = c_acc + ec12, c3 = c_acc + ec123, c4 = rc3;
    float s1 = s_acc + ds0, s2 = s_acc + es12, s3 = s_acc + es123, s4 = rs3;

    float q1 = s1 * c1, q2 = s2 * c2, q3 = s3 * c3, q4 = s4 * c4;
    float q12 = q1 + q2, q123 = q12 + q3, q1234 = q12 + (q3 + q4);
    float w1 = __builtin_fmaf(q1,    DTF, yaw);
    float w2 = __builtin_fmaf(q12,   DTF, yaw);
    float w3 = __builtin_fmaf(q123,  DTF, yaw);
    float w4 = __builtin_fmaf(q1234, DTF, yaw);

    float sn1, cs1, sn2, cs2, sn3, cs3, sn4, cs4;
    fast_sincosf(w1, sn1, cs1);
    fast_sincosf(w2, sn2, cs2);
    fast_sincosf(w3, sn3, cs3);
    fast_sincosf(w4, sn4, cs4);

    float sd1 = s1 * DTF, sd2 = s2 * DTF, sd3 = s3 * DTF, sd4 = s4 * DTF;
    float xi1 = sd1 * cs1, xi2 = sd2 * cs2, xi3 = sd3 * cs3, xi4 = sd4 * cs4;
    float yi1 = sd1 * sn1, yi2 = sd2 * sn2, yi3 = sd3 * sn3, yi4 = sd4 * sn4;
    float xs12 = xi1 + xi2, xs123 = xs12 + xi3, xs1234 = xs12 + (xi3 + xi4);
    float ys12 = yi1 + yi2, ys123 = ys12 + yi3, ys1234 = ys12 + (yi3 + yi4);
    float x1 = x + xi1, x2 = x + xs12, x3 = x + xs123, x4 = x + xs1234;
    float y1 = yy + yi1, y2 = yy + ys12, y3 = yy + ys123, y4 = yy + ys1234;

    float dx1 = x1 - gx, dy1 = y1 - gy, dx2 = x2 - gx, dy2 = y2 - gy;
    float dx3 = x3 - gx, dy3 = y3 - gy, dx4 = x4 - gx, dy4 = y4 - gy;
    float d1 = __builtin_sqrtf(__builtin_fmaf(dy1, dy1, dx1 * dx1));
    float d2 = __builtin_sqrtf(__builtin_fmaf(dy2, dy2, dx2 * dx2));
    float d3 = __builtin_sqrtf(__builtin_fmaf(dy3, dy3, dx3 * dx3));
    float d4 = __builtin_sqrtf(__builtin_fmaf(dy4, dy4, dx4 * dx4));
    dist_sum += (d1 + d2) + (d3 + d4);
    dlast = d4;

    float fx1 = fminf(fmaxf(__builtin_fmaf(x1, 2.5f, 25.f), 0.f), 49.f);
    float fy1 = fminf(fmaxf(__builtin_fmaf(y1, 2.5f, 25.f), 0.f), 49.f);
    float fx2 = fminf(fmaxf(__builtin_fmaf(x2, 2.5f, 25.f), 0.f), 49.f);
    float fy2 = fminf(fmaxf(__builtin_fmaf(y2, 2.5f, 25.f), 0.f), 49.f);
    float fx3 = fminf(fmaxf(__builtin_fmaf(x3, 2.5f, 25.f), 0.f), 49.f);
    float fy3 = fminf(fmaxf(__builtin_fmaf(y3, 2.5f, 25.f), 0.f), 49.f);
    float fx4 = fminf(fmaxf(__builtin_fmaf(x4, 2.5f, 25.f), 0.f), 49.f);
    float fy4 = fminf(fmaxf(__builtin_fmaf(y4, 2.5f, 25.f), 0.f), 49.f);
    map_sum += (pp0 + pp1) + (pp2 + pp3);
    pp0 = s_bev[(int)fy1 * 50 + (int)fx1];
    pp1 = s_bev[(int)fy2 * 50 + (int)fx2];
    pp2 = s_bev[(int)fy3 * 50 + (int)fx3];
    pp3 = s_bev[(int)fy4 * 50 + (int)fx4];
    map_sum += (pp0 + pp1) + (pp2 + pp3);

    a0 = __builtin_fmaf(A0.x, gz,   a0); a1 = __builtin_fmaf(A0.y, gw,   a1);
    a2 = __builtin_fmaf(A0.z, u1.z, a2); a3 = __builtin_fmaf(A0.w, u1.w, a3);
    a0 = __builtin_fmaf(A1.x, u2.z, a0); a1 = __builtin_fmaf(A1.y, u2.w, a1);
    a2 = __builtin_fmaf(A1.z, u3.z, a2); a3 = __builtin_fmaf(A1.w, u3.w, a3);
  }

  const float cost_total =
      map_sum + 0.1f * dist_sum + dlast + (a0 + a2) + (a1 + a3);

  float4 o; o.x = cost_total; o.y = n00; o.z = n01; o.w = 0.f;
  ((float4*)ws)[k] = o;

  float m = cost_total;
  #pragma unroll
  for (int off = 32; off >= 1; off >>= 1) m = fminf(m, __shfl_xor(m, off));
  __shared__ float s_m[TPB / 64];
  if ((tid & 63) == 0) s_m[tid >> 6] = m;
  __syncthreads();
  if (tid == 0) {
    float bm = s_m[0];
    for (int w = 1; w < TPB / 64; ++w) bm = fminf(bm, s_m[w]);
    ws[(size_t)KS * 4 + blockIdx.x] = bm;
  }
}

__global__ __launch_bounds__(TPB) void mppi_weight(
    const float* __restrict__ ws, float* __restrict__ acc)
{
  const int tid = threadIdx.x;
  const float* mins = ws + (size_t)KS * 4;
  float m = mins[tid];
  #pragma unroll
  for (int off = 32; off >= 1; off >>= 1) m = fminf(m, __shfl_xor(m, off));
  __shared__ float s_m[TPB / 64];
  if ((tid & 63) == 0) s_m[tid >> 6] = m;
  __syncthreads();
  const float beta = fminf(fminf(s_m[0], s_m[1]), fminf(s_m[2], s_m[3]));

  const int k = blockIdx.x * TPB + tid;
  const float4 v = ((const float4*)ws)[k];
  const float w = expf(beta - v.x);   /* exp(-(cost-beta)/LAMBDA), LAMBDA=1 */
  float s0 = w, s1 = w * v.y, s2 = w * v.z;
  #pragma unroll
  for (int off = 32; off >= 1; off >>= 1) {
    s0 += __shfl_xor(s0, off);
    s1 += __shfl_xor(s1, off);
    s2 += __shfl_xor(s2, off);
  }
  __shared__ float s_p[TPB / 64][3];
  if ((tid & 63) == 0) { s_p[tid >> 6][0] = s0; s_p[tid >> 6][1] = s1; s_p[tid >> 6][2] = s2; }
  __syncthreads();
  if (tid == 0) {
    float b0 = 0.f, b1 = 0.f, b2 = 0.f;
    for (int w2 = 0; w2 < TPB / 64; ++w2) { b0 += s_p[w2][0]; b1 += s_p[w2][1]; b2 += s_p[w2][2]; }
    atomicAdd(&acc[0], b0); atomicAdd(&acc[1], b1); atomicAdd(&acc[2], b2);
  }
}

__global__ void mppi_final(const float* __restrict__ U,
                           const float* __restrict__ acc,
                           float* __restrict__ out)
{
  if (threadIdx.x == 0) {
    const float inv = 1.0f / acc[0];
    out[0] = U[2] + acc[1] * inv;   /* U_rolled[0] = U_orig[1] */
    out[1] = U[3] + acc[2] * inv;
  }
}

extern "C" void kernel_launch(void* const* d_in, const int* in_sizes, int n_in,
                              void* d_out, int out_size, void* d_ws, size_t ws_size,
                              hipStream_t stream)
{
  const float* state = (const float*)d_in[0];
  const float* U     = (const float*)d_in[1];
  const float* noise = (const float*)d_in[2];
  const float* nsi   = (const float*)d_in[3];
  const float* bev   = (const float*)d_in[4];
  const float* goal  = (const float*)d_in[5];
  /* d_in[6] (last_action) only writes state[15:17] -> never affects output */

  float* ws  = (float*)d_ws;
  float* out = (float*)d_out;
  float* acc = ws + (size_t)KS * 4 + NBLK;

  mppi_rollout<<<NBLK, TPB, 0, stream>>>(state, U, noise, nsi, bev, goal, ws);
  mppi_weight<<<NBLK, TPB, 0, stream>>>(ws, acc);
  mppi_final<<<1, 64, 0, stream>>>(U, acc, out);
}

// Round 7
// 121.633 us; speedup vs baseline: 1.0007x; 1.0007x over previous
//
#include <hip/hip_runtime.h>
#include <math.h>

#define KS     65536
#define TS     96
#define TPB    256
#define NT     4                    /* threads per sample (chunked scan) */
#define NBLK   ((KS * NT) / TPB)    /* 1024 rollout blocks */
#define MINS_N NBLK
#define W_TPB  256
#define W_NBLK (KS / W_TPB)         /* 256 */

#define MSR 0.196f                  /* 9.8 * 0.02 (f64 -> f32) */
#define WSM 17.0f
#define DTF 0.02f

/* Branchless sincos: Cody-Waite pi/2 reduction + Taylor deg-7/8. err ~1e-7 */
static __device__ __forceinline__ void fast_sincosf(float x, float& s, float& c) {
  float nf = __builtin_rintf(x * 0.63661977f);
  int   q  = (int)nf;
  float r  = __builtin_fmaf(nf, -1.5703125f, x);
  r = __builtin_fmaf(nf, -4.837512969970703125e-4f, r);
  r = __builtin_fmaf(nf, -7.54978995489188216e-8f, r);
  float r2 = r * r;
  float sw = __builtin_fmaf(r2, -1.98412698e-4f, 8.33333310e-3f);
  sw = __builtin_fmaf(r2, sw, -1.66666672e-1f);
  sw = __builtin_fmaf(r2, sw, 1.0f);
  float sinr = r * sw;
  float cw = __builtin_fmaf(r2, 2.48015873e-5f, -1.38888889e-3f);
  cw = __builtin_fmaf(r2, cw, 4.16666679e-2f);
  cw = __builtin_fmaf(r2, cw, -0.5f);
  float cosr = __builtin_fmaf(r2, cw, 1.0f);
  const bool swq = (q & 1) != 0;
  float sb = swq ? cosr : sinr;
  float cb = swq ? sinr : cosr;
  unsigned ssign = ((unsigned)q << 30) & 0x80000000u;
  unsigned csign = ((unsigned)(q + 1) << 30) & 0x80000000u;
  s = __uint_as_float(__float_as_uint(sb) ^ ssign);
  c = __uint_as_float(__float_as_uint(cb) ^ csign);
}

static __device__ __forceinline__ float clipc(float v, float b) {
  return fminf(fmaxf(v, -b), b);
}

/* ws layout (floats):
   [0, KS*4)               per-k {cost_total, noise[k,0,0], noise[k,0,1], pad}
   [KS*4, KS*4+MINS_N)     per-block cost min (1024)
   [KS*4+MINS_N, +3)       accumulators {sum_w, sum_w*n0, sum_w*n1}         */

__global__ __launch_bounds__(TPB, 4) void mppi_rollout(
    const float* __restrict__ state, const float* __restrict__ U,
    const float* __restrict__ noise, const float* __restrict__ nsi,
    const float* __restrict__ bev,   const float* __restrict__ goal,
    float* __restrict__ ws)
{
  const float MCRf = (float)(tan(30.0 / 57.3) / (0.24 + 0.24) * 20.0 * 0.02);

  __shared__ float  s_bev[2500];
  __shared__ float4 s_ug[100];   /* {u0*MCR, u1*WSM, g0, g1} at 25*(t/24)+t%24 */

  const int tid = threadIdx.x;
  if (tid < TS) {
    float u0 = 0.f, u1 = 0.f;
    if (tid < TS - 1) { u0 = U[(tid + 1) * 2 + 0]; u1 = U[(tid + 1) * 2 + 1]; }
    float4 g;
    g.x = u0 * MCRf; g.y = u1 * WSM;
    g.z = u0 * nsi[0] + u1 * nsi[1];
    g.w = u0 * nsi[2] + u1 * nsi[3];
    s_ug[tid + tid / 24] = g;    /* pad stride 25 -> conflict-free b128 reads */
  }
  for (int i = tid; i < 2500; i += TPB) s_bev[i] = bev[i];
  if (blockIdx.x == 0 && tid < 3) ws[(size_t)KS * 4 + MINS_N + tid] = 0.f;
  __syncthreads();

  const int gid  = blockIdx.x * TPB + tid;
  const int k    = gid >> 2;          /* sample */
  const int c    = gid & 3;           /* chunk: t in [24c, 24c+23] */
  const int lane = tid & 63;
  const int ugb  = 25 * c;

  const float4* __restrict__ nrow = (const float4*)noise + (size_t)k * 48 + c * 12;

  const float gx = goal[0], gy = goal[1];
  const float stx = state[0], sty = state[1], st5 = state[5];

  /* ---- phase 1: raw -> clipped diffs -> LOCAL cumsums (serial, 24 steps) */
  float lc[24], ls[24];
  float ccum = 0.f, scum = 0.f;
  float ac0 = 0.f, ac1 = 0.f, n00 = 0.f, n01 = 0.f;
  float rawc0 = 0.f, raws0 = 0.f, pc = 0.f, ps = 0.f;
  #pragma unroll
  for (int j2 = 0; j2 < 12; ++j2) {
    float4 nv = nrow[j2];
    float4 ga = s_ug[ugb + 2 * j2];
    float4 gb = s_ug[ugb + 2 * j2 + 1];
    float rca = __builtin_fmaf(nv.x, MCRf, ga.x);
    float rsa = __builtin_fmaf(nv.y, WSM,  ga.y);
    float rcb = __builtin_fmaf(nv.z, MCRf, gb.x);
    float rsb = __builtin_fmaf(nv.w, WSM,  gb.y);
    ac0 = __builtin_fmaf(nv.x, ga.z, ac0);
    ac1 = __builtin_fmaf(nv.y, ga.w, ac1);
    ac0 = __builtin_fmaf(nv.z, gb.z, ac0);
    ac1 = __builtin_fmaf(nv.w, gb.w, ac1);
    if (j2 == 0) { rawc0 = rca; raws0 = rsa; n00 = nv.x; n01 = nv.y; }
    else {
      ccum += clipc(rca - pc, MCRf); lc[2 * j2 - 1] = ccum;
      scum += clipc(rsa - ps, MSR);  ls[2 * j2 - 1] = scum;
    }
    ccum += clipc(rcb - rca, MCRf); lc[2 * j2] = ccum;
    scum += clipc(rsb - rsa, MSR);  ls[2 * j2] = scum;
    pc = rcb; ps = rsb;
  }
  /* chunk-boundary diff: raw[T0+24] = next chunk's raw[0] (c<3 only) */
  {
    float nxc = __shfl_down(rawc0, 1);
    float nxs = __shfl_down(raws0, 1);
    ccum += (c < 3) ? clipc(nxc - pc, MCRf) : 0.f;  lc[23] = ccum;
    scum += (c < 3) ? clipc(nxs - ps, MSR)  : 0.f;  ls[23] = scum;
  }
  /* cross-chunk exclusive prefix of totals (width-4 shfl groups) */
  float coff, soff;
  {
    float ic = ccum, is_ = scum;
    float a = __shfl_up(ic, 1, 4);  ic  += (c >= 1) ? a : 0.f;
    float b = __shfl_up(is_, 1, 4); is_ += (c >= 1) ? b : 0.f;
    float d = __shfl_up(ic, 2, 4);  ic  += (c >= 2) ? d : 0.f;
    float e = __shfl_up(is_, 2, 4); is_ += (c >= 2) ? e : 0.f;
    coff = ic - ccum; soff = is_ - scum;
  }

  /* ---- phase 2: absolute c,s; yaw local cumsum */
  float yl[24];
  float ycum = 0.f;
  #pragma unroll
  for (int j = 0; j < 24; ++j) {
    float cR = coff + lc[j];
    float sR = soff + ls[j];
    if (j == 23) {               /* t=95: c,s = raw last (un-rate-limited) */
      cR = (c == 3) ? pc : cR;
      sR = (c == 3) ? ps : sR;
    }
    lc[j] = cR; ls[j] = sR;      /* overwrite with absolute values */
    ycum = __builtin_fmaf(cR * sR, DTF, ycum);
    yl[j] = ycum;
  }
  float yoff;
  {
    float iy = ycum;
    float a = __shfl_up(iy, 1, 4); iy += (c >= 1) ? a : 0.f;
    float b = __shfl_up(iy, 2, 4); iy += (c >= 2) ? b : 0.f;
    yoff = iy - ycum;
  }

  /* ---- phase 3: sincos; x,y local cumsums (reuse lc/ls storage) */
  float xcum = 0.f, pcum = 0.f;
  #pragma unroll
  for (int j = 0; j < 24; ++j) {
    float yawj = st5 + (yoff + yl[j]);
    float sn, cs;
    fast_sincosf(yawj, sn, cs);
    float sdt = ls[j] * DTF;
    xcum = __builtin_fmaf(sdt, cs, xcum);
    pcum = __builtin_fmaf(sdt, sn, pcum);
    lc[j] = xcum; ls[j] = pcum;
  }
  float xoff, poff;
  {
    float ix = xcum, ip = pcum;
    float a = __shfl_up(ix, 1, 4); ix += (c >= 1) ? a : 0.f;
    float b = __shfl_up(ip, 1, 4); ip += (c >= 1) ? b : 0.f;
    float d = __shfl_up(ix, 2, 4); ix += (c >= 2) ? d : 0.f;
    float e = __shfl_up(ip, 2, 4); ip += (c >= 2) ? e : 0.f;
    xoff = ix - xcum; poff = ip - pcum;
  }

  /* ---- phase 4: absolute x,y; dist + BEV + cost */
  float dsum = 0.f, m0 = 0.f, m1 = 0.f, m2 = 0.f, m3 = 0.f, dl = 0.f;
  #pragma unroll
  for (int j = 0; j < 24; ++j) {
    float x = stx + (xoff + lc[j]);
    float y = sty + (poff + ls[j]);
    float dx = x - gx, dy = y - gy;
    float dist = __builtin_sqrtf(__builtin_fmaf(dy, dy, dx * dx));
    dsum += dist;
    float fx = fminf(fmaxf(__builtin_fmaf(x, 2.5f, 25.f), 0.f), 49.f);
    float fy = fminf(fmaxf(__builtin_fmaf(y, 2.5f, 25.f), 0.f), 49.f);
    float g = s_bev[(int)fy * 50 + (int)fx];
    if ((j & 3) == 0) m0 += g; else if ((j & 3) == 1) m1 += g;
    else if ((j & 3) == 2) m2 += g; else m3 += g;
    if (j == 23) dl = dist;
  }
  float dterm = (c == 3) ? dl : 0.f;  /* terminal = dist at t=95 */

  float cost = ((m0 + m1) + (m2 + m3)) + 0.1f * dsum + (ac0 + ac1) + dterm;
  cost += __shfl_xor(cost, 1, 4);
  cost += __shfl_xor(cost, 2, 4);     /* all 4 lanes: sample total */

  if (c == 0) {
    float4 o; o.x = cost; o.y = n00; o.z = n01; o.w = 0.f;
    ((float4*)ws)[k] = o;
  }

  /* block-level min (each sample counted 4x — harmless for min) */
  float m = cost;
  #pragma unroll
  for (int off = 32; off >= 1; off >>= 1) m = fminf(m, __shfl_xor(m, off));
  __shared__ float s_m[TPB / 64];
  if ((tid & 63) == 0) s_m[tid >> 6] = m;
  __syncthreads();
  if (tid == 0) {
    float bm = s_m[0];
    for (int w = 1; w < TPB / 64; ++w) bm = fminf(bm, s_m[w]);
    ws[(size_t)KS * 4 + blockIdx.x] = bm;
  }
}

__global__ __launch_bounds__(W_TPB) void mppi_weight(
    const float* __restrict__ ws, float* __restrict__ acc)
{
  const int tid = threadIdx.x;
  /* beta: every block redundantly reduces the 1024 block mins (L2-hot) */
  const float* mins = ws + (size_t)KS * 4;
  float m = 3.4028235e38f;
  for (int i = tid; i < MINS_N; i += W_TPB) m = fminf(m, mins[i]);
  #pragma unroll
  for (int off = 32; off >= 1; off >>= 1) m = fminf(m, __shfl_xor(m, off));
  __shared__ float s_m[W_TPB / 64];
  if ((tid & 63) == 0) s_m[tid >> 6] = m;
  __syncthreads();
  const float beta = fminf(fminf(s_m[0], s_m[1]), fminf(s_m[2], s_m[3]));

  const int k = blockIdx.x * W_TPB + tid;
  const float4 v = ((const float4*)ws)[k];
  const float w = expf(beta - v.x);   /* exp(-(cost-beta)/LAMBDA), LAMBDA=1 */
  float s0 = w, s1 = w * v.y, s2 = w * v.z;
  #pragma unroll
  for (int off = 32; off >= 1; off >>= 1) {
    s0 += __shfl_xor(s0, off);
    s1 += __shfl_xor(s1, off);
    s2 += __shfl_xor(s2, off);
  }
  __shared__ float s_p[W_TPB / 64][3];
  if ((tid & 63) == 0) { s_p[tid >> 6][0] = s0; s_p[tid >> 6][1] = s1; s_p[tid >> 6][2] = s2; }
  __syncthreads();
  if (tid == 0) {
    float b0 = 0.f, b1 = 0.f, b2 = 0.f;
    for (int w2 = 0; w2 < W_TPB / 64; ++w2) { b0 += s_p[w2][0]; b1 += s_p[w2][1]; b2 += s_p[w2][2]; }
    atomicAdd(&acc[0], b0); atomicAdd(&acc[1], b1); atomicAdd(&acc[2], b2);
  }
}

__global__ void mppi_final(const float* __restrict__ U,
                           const float* __restrict__ acc,
                           float* __restrict__ out)
{
  if (threadIdx.x == 0) {
    const float inv = 1.0f / acc[0];
    out[0] = U[2] + acc[1] * inv;   /* U_rolled[0] = U_orig[1] */
    out[1] = U[3] + acc[2] * inv;
  }
}

extern "C" void kernel_launch(void* const* d_in, const int* in_sizes, int n_in,
                              void* d_out, int out_size, void* d_ws, size_t ws_size,
                              hipStream_t stream)
{
  const float* state = (const float*)d_in[0];
  const float* U     = (const float*)d_in[1];
  const float* noise = (const float*)d_in[2];
  const float* nsi   = (const float*)d_in[3];
  const float* bev   = (const float*)d_in[4];
  const float* goal  = (const float*)d_in[5];
  /* d_in[6] (last_action) only writes state[15:17] -> never affects output */

  float* ws  = (float*)d_ws;
  float* out = (float*)d_out;
  float* acc = ws + (size_t)KS * 4 + MINS_N;

  mppi_rollout<<<NBLK, TPB, 0, stream>>>(state, U, noise, nsi, bev, goal, ws);
  mppi_weight<<<W_NBLK, W_TPB, 0, stream>>>(ws, acc);
  mppi_final<<<1, 64, 0, stream>>>(U, acc, out);
}